// Round 2
// baseline (690.785 us; speedup 1.0000x reference)
//
#include <hip/hip_runtime.h>
#include <cstdint>
#include <cstddef>

typedef __bf16 bf16;
typedef __bf16 bf16x4 __attribute__((ext_vector_type(4)));
typedef __bf16 bf16x8 __attribute__((ext_vector_type(8)));
typedef float  f32x4  __attribute__((ext_vector_type(4)));
typedef long long i64v;

#define NROWS   32768   // 4096 * 8  (X2 rows)
#define DBLK    512
#define H1N     1024
#define H2N     512
#define NEXP    6
#define NBATCH  4096
#define HALL    (NEXP * H1N)   // 6144 h1 cols across all experts
#define W2SCALE 32.0f
#define W2INV   0.03125f

// async global->LDS, 16B per lane; LDS dest = wave-uniform base + lane*16
__device__ __forceinline__ void gld16(const void* g, void* l) {
    __builtin_amdgcn_global_load_lds(
        (const __attribute__((address_space(1))) void*)g,
        (__attribute__((address_space(3))) void*)l, 16, 0, 0);
}

// inf-safe fast tanh: 1 - 2/(exp(2x)+1); exp2+rcp form (3 full-rate + 2 trans)
__device__ __forceinline__ float fast_tanh(float x) {
    float e = __builtin_amdgcn_exp2f(x * 2.8853900817779268f);  // e^{2x}
    float r = __builtin_amdgcn_rcpf(e + 1.0f);
    return __builtin_fmaf(-2.0f, r, 1.0f);
}

__device__ __forceinline__ float hsum16(float v) {
    v += __shfl_xor(v, 1);
    v += __shfl_xor(v, 2);
    v += __shfl_xor(v, 4);
    v += __shfl_xor(v, 8);
    return v;
}

// fp8 tiles: 64B rows, 4 granules; granule g of row r lives at g^((r>>1)&3)
__device__ __forceinline__ int swz8(int row, int g) {
    return row * 64 + ((g ^ ((row >> 1) & 3)) << 4);
}

// ---------------- prep kernels ----------------

__global__ void cvt_bf16_kernel(const float* __restrict__ in,
                                bf16* __restrict__ out, int n4) {
    int i = blockIdx.x * blockDim.x + threadIdx.x;
    if (i >= n4) return;
    float4 v = ((const float4*)in)[i];
    bf16x4 o;
    o.x = (bf16)v.x; o.y = (bf16)v.y; o.z = (bf16)v.z; o.w = (bf16)v.w;
    ((bf16x4*)out)[i] = o;
}

// in: [E][K][N] f32 -> out: [E][N][K] bf16 (LDS-tiled transpose)
__global__ __launch_bounds__(256) void transpose_cvt(
    const float* __restrict__ in, bf16* __restrict__ out, int K, int N) {
    __shared__ bf16 tile[64][66];
    int e  = blockIdx.z;
    int n0 = blockIdx.x * 64;
    int k0 = blockIdx.y * 64;
    int c  = threadIdx.x & 63;
    int rb = threadIdx.x >> 6;   // 0..3
    const float* src = in + (size_t)e * K * N;
    bf16* dst = out + (size_t)e * N * K;
#pragma unroll
    for (int it = 0; it < 16; ++it) {
        int k = k0 + rb + it * 4;
        int n = n0 + c;
        if (k < K && n < N) tile[rb + it * 4][c] = (bf16)src[(size_t)k * N + n];
    }
    __syncthreads();
#pragma unroll
    for (int it = 0; it < 16; ++it) {
        int n = n0 + rb + it * 4;
        int k = k0 + c;
        if (n < N && k < K) dst[(size_t)n * K + k] = tile[c][rb + it * 4];
    }
}

// in: [E][K][N] f32 -> out: [E][N][K] fp8 e4m3, scaled
__global__ __launch_bounds__(256) void transpose_cvt_fp8(
    const float* __restrict__ in, uint8_t* __restrict__ out, int K, int N,
    float scale) {
    __shared__ float tile[64][65];
    int e  = blockIdx.z;
    int n0 = blockIdx.x * 64;
    int k0 = blockIdx.y * 64;
    int c  = threadIdx.x & 63;
    int rb = threadIdx.x >> 6;   // 0..3
    const float* src = in + (size_t)e * K * N;
    uint8_t* dst = out + (size_t)e * N * K;
#pragma unroll
    for (int it = 0; it < 16; ++it) {
        int k = k0 + rb + it * 4;
        int n = n0 + c;
        if (k < K && n < N) tile[rb + it * 4][c] = src[(size_t)k * N + n];
    }
    __syncthreads();
#pragma unroll
    for (int it = 0; it < 16; ++it) {
        int n = n0 + rb + it * 4;
        int k = k0 + c;
        if (n < N && k < K) {
            float v = tile[c][rb + it * 4] * scale;
            int p = __builtin_amdgcn_cvt_pk_fp8_f32(v, v, 0, false);
            dst[(size_t)n * K + k] = (uint8_t)(p & 0xff);
        }
    }
}

__global__ void zero_f32_kernel(float* __restrict__ p, int n) {
    int i = blockIdx.x * blockDim.x + threadIdx.x;
    if (i < n) p[i] = 0.0f;
}

// ---------------- router ----------------

__global__ __launch_bounds__(256, 2) void router_kernel(
    const bf16* __restrict__ xbf,   // [4096][4096]
    const bf16* __restrict__ Wr1t,  // [8][32][512]
    const float* __restrict__ br1,  // [8][32]
    const float* __restrict__ Wr2,  // [8][32][6]
    const float* __restrict__ br2,  // [8][6]
    float* __restrict__ routing) {  // [32768][6]
    __shared__ __align__(16) bf16 sA[128 * 64];
    __shared__ __align__(16) bf16 sB[32 * 64];
    const int tid = threadIdx.x;
    const int w = tid >> 6, l = tid & 63;
    const int s  = blockIdx.y;
    const int b0 = blockIdx.x * 128;
    const int wm = w * 32;
    const int srow = l >> 3, schk = (l & 7) * 8;
    const int fr = l & 15, fq = l >> 4;
    const bf16* Ab = xbf + (size_t)s * 512;
    const bf16* Bb = Wr1t + (size_t)s * (32 * 512);

    f32x4 acc[2][2];
#pragma unroll
    for (int i = 0; i < 2; ++i)
#pragma unroll
        for (int j = 0; j < 2; ++j) acc[i][j] = (f32x4){0.f, 0.f, 0.f, 0.f};

    for (int k0 = 0; k0 < 512; k0 += 64) {
        __syncthreads();
#pragma unroll
        for (int jj = 0; jj < 4; ++jj) {
            int row = w * 32 + jj * 8;
            gld16(Ab + (size_t)(b0 + row + srow) * 4096 + k0 + schk, sA + row * 64);
        }
        gld16(Bb + (size_t)(w * 8 + srow) * 512 + k0 + schk, sB + w * 8 * 64);
        __syncthreads();
#pragma unroll
        for (int ks = 0; ks < 2; ++ks) {
            bf16x8 af[2], bfr[2];
#pragma unroll
            for (int i = 0; i < 2; ++i)
                af[i] = *(const bf16x8*)&sA[(wm + i * 16 + fr) * 64 + ks * 32 + fq * 8];
#pragma unroll
            for (int j = 0; j < 2; ++j)
                bfr[j] = *(const bf16x8*)&sB[(j * 16 + fr) * 64 + ks * 32 + fq * 8];
#pragma unroll
            for (int i = 0; i < 2; ++i)
#pragma unroll
                for (int j = 0; j < 2; ++j)
                    acc[i][j] = __builtin_amdgcn_mfma_f32_16x16x32_bf16(
                        af[i], bfr[j], acc[i][j], 0, 0, 0);
        }
    }

    float b1v[2], w2v[2][6], br2v[6];
#pragma unroll
    for (int j = 0; j < 2; ++j) {
        int col = j * 16 + fr;
        b1v[j] = br1[s * 32 + col];
#pragma unroll
        for (int e2 = 0; e2 < 6; ++e2) w2v[j][e2] = Wr2[(s * 32 + col) * 6 + e2];
    }
#pragma unroll
    for (int e2 = 0; e2 < 6; ++e2) br2v[e2] = br2[s * 6 + e2];

#pragma unroll
    for (int i = 0; i < 2; ++i) {
#pragma unroll
        for (int r = 0; r < 4; ++r) {
            float lg[6] = {0.f, 0.f, 0.f, 0.f, 0.f, 0.f};
#pragma unroll
            for (int j = 0; j < 2; ++j) {
                float t = fmaxf(acc[i][j][r] + b1v[j], 0.f);
#pragma unroll
                for (int e2 = 0; e2 < 6; ++e2) lg[e2] += t * w2v[j][e2];
            }
#pragma unroll
            for (int e2 = 0; e2 < 6; ++e2) lg[e2] = hsum16(lg[e2]) + br2v[e2];
            float mx = lg[0];
#pragma unroll
            for (int e2 = 1; e2 < 6; ++e2) mx = fmaxf(mx, lg[e2]);
            float p[6], sum = 0.f;
#pragma unroll
            for (int e2 = 0; e2 < 6; ++e2) { p[e2] = __expf(lg[e2] - mx); sum += p[e2]; }
            float inv = __fdividef(1.f, sum);
            if (fr == 0) {
                int brow = b0 + wm + i * 16 + fq * 4 + r;
                float* dst = routing + ((size_t)brow * 8 + s) * 6;
#pragma unroll
                for (int e2 = 0; e2 < 6; ++e2) dst[e2] = p[e2] * inv;
            }
        }
    }
}

// ------- expert layer 1: h1[xrow][col] = fp8(tanh(W1t@X^T+b)) -------
// R2: 16-phase 4-slot ring pipeline. 256x256 tile, 512 threads (8 waves
// 2m x 4n), K split into 16 slots of 32 (one MFMA k-slice per phase).
// LDS = 2 operands x 4 slots x 16 KB = 128 KB. Stage lead = 3 slots,
// counted vmcnt(8) (waits loads issued ~2 phases earlier), ONE barrier
// per phase (end-of-phase barrier carries both overwrite protection and
// cross-wave staging visibility), setprio around the 32-MFMA cluster.
__global__ __launch_bounds__(512, 2) void gemm1_kernel(
    const bf16* __restrict__ A,     // [6144][512] (W1t, all experts)
    const bf16* __restrict__ B,     // xbf [32768][512]
    const float* __restrict__ bias, // [6144]
    uint8_t* __restrict__ h1,       // [32768][6144] fp8
    int ldh) {
    __shared__ __align__(16) bf16 sA[4][256 * 32];   // 4 x 16 KB
    __shared__ __align__(16) bf16 sB[4][256 * 32];   // 4 x 16 KB
    const int tid = threadIdx.x;
    const int w = tid >> 6, l = tid & 63;
    // XCD-chunked block swizzle (nwg = 3072 = 8*384, bijective)
    const int bid = blockIdx.y * 128 + blockIdx.x;
    const int nid = (bid & 7) * 384 + (bid >> 3);
    const int n0 = (nid & 127) * 256;   // xrows
    const int m0 = (nid >> 7) * 256;    // h1 cols
    const int wm = (w & 1) * 128;       // 2 wave-cols in m
    const int wn = (w >> 1) * 64;       // 4 wave-rows in n
    const int fr = l & 15, fq = l >> 4;

    // staging: slot rows 64B (32 bf16); per instr 16 rows, lane covers
    // row l>>2, dest granule l&3; source granule = (l&3)^((row>>1)&3)
    const int srow = l >> 2;
    const int dg   = l & 3;
    const int lrow0 = w * 32 + srow;
    const int lrow1 = w * 32 + 16 + srow;
    const int sg0 = dg ^ ((lrow0 >> 1) & 3);
    const int sg1 = dg ^ ((lrow1 >> 1) & 3);
    const bf16* Asrc0 = A + (size_t)(m0 + lrow0) * DBLK + sg0 * 8;
    const bf16* Asrc1 = A + (size_t)(m0 + lrow1) * DBLK + sg1 * 8;
    const bf16* Bsrc0 = B + (size_t)(n0 + lrow0) * DBLK + sg0 * 8;
    const bf16* Bsrc1 = B + (size_t)(n0 + lrow1) * DBLK + sg1 * 8;
    const int ldsA0 = (w * 32) * 32;        // element offsets of dest bases
    const int ldsA1 = (w * 32 + 16) * 32;

    // ds_read element offsets (constant per thread): row*32 + swz-granule*8
    int aoff[8], boff[4];
#pragma unroll
    for (int i = 0; i < 8; ++i) {
        int r = wm + i * 16 + fr;
        aoff[i] = r * 32 + ((fq ^ ((r >> 1) & 3)) * 8);
    }
#pragma unroll
    for (int j = 0; j < 4; ++j) {
        int r = wn + j * 16 + fr;
        boff[j] = r * 32 + ((fq ^ ((r >> 1) & 3)) * 8);
    }

    f32x4 acc[8][4];
#pragma unroll
    for (int i = 0; i < 8; ++i)
#pragma unroll
        for (int j = 0; j < 4; ++j) acc[i][j] = (f32x4){0.f, 0.f, 0.f, 0.f};

    // prologue: stage slots 0,1,2 (4 gld16 per wave per slot)
#pragma unroll
    for (int s = 0; s < 3; ++s) {
        gld16(Asrc0 + s * 32, &sA[s][ldsA0]);
        gld16(Asrc1 + s * 32, &sA[s][ldsA1]);
        gld16(Bsrc0 + s * 32, &sB[s][ldsA0]);
        gld16(Bsrc1 + s * 32, &sB[s][ldsA1]);
    }
    asm volatile("s_waitcnt vmcnt(8)" ::: "memory");   // slot 0 landed
    __builtin_amdgcn_s_barrier();
    __builtin_amdgcn_sched_barrier(0);

#pragma unroll
    for (int t = 0; t < 16; ++t) {
        const int sl = t & 3;
        bf16x8 af[8], bfr[4];
#pragma unroll
        for (int i = 0; i < 8; ++i)
            af[i] = *(const bf16x8*)&sA[sl][aoff[i]];
#pragma unroll
        for (int j = 0; j < 4; ++j)
            bfr[j] = *(const bf16x8*)&sB[sl][boff[j]];
        if (t < 13) {
            const int s2 = (t + 3) & 3;
            const int ko = (t + 3) * 32;
            gld16(Asrc0 + ko, &sA[s2][ldsA0]);
            gld16(Asrc1 + ko, &sA[s2][ldsA1]);
            gld16(Bsrc0 + ko, &sB[s2][ldsA0]);
            gld16(Bsrc1 + ko, &sB[s2][ldsA1]);
            asm volatile("s_waitcnt vmcnt(8)" ::: "memory");  // slot t+1 landed
        } else if (t == 13) {
            asm volatile("s_waitcnt vmcnt(4)" ::: "memory");  // slot 14 landed
        } else {
            asm volatile("s_waitcnt vmcnt(0)" ::: "memory");  // slot 15 landed
        }
        __builtin_amdgcn_sched_barrier(0);
        __builtin_amdgcn_s_setprio(1);
#pragma unroll
        for (int i = 0; i < 8; ++i)
#pragma unroll
            for (int j = 0; j < 4; ++j)
                acc[i][j] = __builtin_amdgcn_mfma_f32_16x16x32_bf16(
                    af[i], bfr[j], acc[i][j], 0, 0, 0);
        __builtin_amdgcn_s_setprio(0);
        __builtin_amdgcn_s_barrier();
        __builtin_amdgcn_sched_barrier(0);
    }

    // epilogue: j-outer / i-inner so each 64B h1 line is completed by 4
    // back-to-back 16B bursts (kills partial-line write amplification)
    float4 bb[8];
#pragma unroll
    for (int i = 0; i < 8; ++i)
        bb[i] = *(const float4*)&bias[m0 + wm + i * 16 + fq * 4];
#pragma unroll
    for (int j = 0; j < 4; ++j) {
        int xrow = n0 + wn + j * 16 + fr;
        uint8_t* dst = &h1[(size_t)xrow * ldh + m0 + wm + fq * 4];
#pragma unroll
        for (int i = 0; i < 8; ++i) {
            float t0 = fast_tanh(acc[i][j][0] + bb[i].x);
            float t1 = fast_tanh(acc[i][j][1] + bb[i].y);
            float t2 = fast_tanh(acc[i][j][2] + bb[i].z);
            float t3 = fast_tanh(acc[i][j][3] + bb[i].w);
            int p = 0;
            p = __builtin_amdgcn_cvt_pk_fp8_f32(t0, t1, p, false);
            p = __builtin_amdgcn_cvt_pk_fp8_f32(t2, t3, p, true);
            *(uint32_t*)(dst + i * 16) = (uint32_t)p;
        }
    }
}

// ------- layer 2+3 (fp8 x fp8): eo += tanh(h1@W2+b)@We3 -------
// A = W2f8t rows (h2 cols, x32-scaled), B = h1 rows (fp8, col band e*1024).
__global__ __launch_bounds__(256, 4) void gemm2_kernel(
    const uint8_t* __restrict__ h1,    // [32768][6144] fp8
    const uint8_t* __restrict__ W2f8t, // [6][512][1024] fp8 (x32)
    const float* __restrict__ be2,     // [6][512]
    const float* __restrict__ We3,     // [6][512][3]
    float* __restrict__ eo,            // [6][32768][3]
    int ldh) {
    __shared__ __align__(16) uint8_t sA[128 * 64];
    __shared__ __align__(16) uint8_t sB[128 * 64];
    __shared__ float w3s[128 * 3];
    __shared__ float b2s[128];
    const int tid = threadIdx.x;
    const int w = tid >> 6, l = tid & 63;
    const int e  = blockIdx.z;
    const int n0 = blockIdx.x * 128;   // xrows
    const int m0 = blockIdx.y * 128;   // h2 cols (0..511)
    const int wm = (w & 1) * 64, wn = (w >> 1) * 64;
    const int srow4 = l >> 2;                         // dest row within 16-row group
    const int g4 = (((l & 3) ^ ((l >> 3) & 3)) << 4); // source granule (matches swz8)
    const int fr = l & 15, fq = l >> 4;
    const uint8_t* Ae = W2f8t + (size_t)e * (H2N * H1N);
    const uint8_t* Be = h1 + (size_t)e * H1N;   // column band within ldh=6144

    if (tid < 128) {
        int c = m0 + tid;
        b2s[tid] = be2[e * H2N + c];
        w3s[tid * 3 + 0] = We3[((size_t)e * H2N + c) * 3 + 0];
        w3s[tid * 3 + 1] = We3[((size_t)e * H2N + c) * 3 + 1];
        w3s[tid * 3 + 2] = We3[((size_t)e * H2N + c) * 3 + 2];
    }

    f32x4 acc[4][4];
#pragma unroll
    for (int i = 0; i < 4; ++i)
#pragma unroll
        for (int j = 0; j < 4; ++j) acc[i][j] = (f32x4){0.f, 0.f, 0.f, 0.f};

    for (int k0 = 0; k0 < H1N; k0 += 64) {
        __syncthreads();
#pragma unroll
        for (int jj = 0; jj < 2; ++jj) {
            int row = w * 32 + jj * 16 + srow4;
            gld16(Ae + (size_t)(m0 + row) * H1N + k0 + g4, sA + (w * 32 + jj * 16) * 64);
            gld16(Be + (size_t)(n0 + row) * ldh + k0 + g4, sB + (w * 32 + jj * 16) * 64);
        }
        __syncthreads();
#pragma unroll
        for (int ks = 0; ks < 2; ++ks) {
            i64v af[4], bfr[4];
#pragma unroll
            for (int i = 0; i < 4; ++i) {
                int row = wm + i * 16 + fr;
                af[i] = *(const i64v*)&sA[swz8(row, ks * 2 + (fq >> 1)) + ((fq & 1) << 3)];
            }
#pragma unroll
            for (int j = 0; j < 4; ++j) {
                int row = wn + j * 16 + fr;
                bfr[j] = *(const i64v*)&sB[swz8(row, ks * 2 + (fq >> 1)) + ((fq & 1) << 3)];
            }
#pragma unroll
            for (int i = 0; i < 4; ++i)
#pragma unroll
                for (int j = 0; j < 4; ++j)
                    acc[i][j] = __builtin_amdgcn_mfma_f32_16x16x32_fp8_fp8(
                        af[i], bfr[j], acc[i][j], 0, 0, 0);
        }
    }

    // lane holds 16 h2-cols of xrow; layer-3 col-sum in-register; acc is x32-scaled
    float p[4][3];
#pragma unroll
    for (int j = 0; j < 4; ++j) { p[j][0] = 0.f; p[j][1] = 0.f; p[j][2] = 0.f; }
#pragma unroll
    for (int i = 0; i < 4; ++i) {
        int cl = wm + i * 16 + fq * 4;   // local col 0..127
        float4 bb = *(const float4*)&b2s[cl];
        float4 wa = *(const float4*)&w3s[cl * 3 + 0];
        float4 wb = *(const float4*)&w3s[cl * 3 + 4];
        float4 wc = *(const float4*)&w3s[cl * 3 + 8];
        float bias4[4] = {bb.x, bb.y, bb.z, bb.w};
        float w30[4] = {wa.x, wa.w, wb.z, wc.y};
        float w31[4] = {wa.y, wb.x, wb.w, wc.z};
        float w32[4] = {wa.z, wb.y, wc.x, wc.w};
#pragma unroll
        for (int j = 0; j < 4; ++j) {
#pragma unroll
            for (int r = 0; r < 4; ++r) {
                float t = fast_tanh(acc[i][j][r] * W2INV + bias4[r]);
                p[j][0] += t * w30[r];
                p[j][1] += t * w31[r];
                p[j][2] += t * w32[r];
            }
        }
    }
#pragma unroll
    for (int j = 0; j < 4; ++j) {
        float v0 = p[j][0], v1 = p[j][1], v2 = p[j][2];
        v0 += __shfl_xor(v0, 16); v0 += __shfl_xor(v0, 32);
        v1 += __shfl_xor(v1, 16); v1 += __shfl_xor(v1, 32);
        v2 += __shfl_xor(v2, 16); v2 += __shfl_xor(v2, 32);
        if (fq == 0) {
            int xrow = n0 + wn + j * 16 + fr;
            float* dst = eo + ((size_t)e * NROWS + xrow) * 3;
            atomicAdd(dst + 0, v0);
            atomicAdd(dst + 1, v1);
            atomicAdd(dst + 2, v2);
        }
    }
}

// ---------------- final: routing-weighted mean + aggregator MLP ----------------
__global__ void final_kernel(
    const float* __restrict__ routing, const float* __restrict__ eo,
    const float* __restrict__ be3, const float* __restrict__ Wa1,
    const float* __restrict__ ba1, const float* __restrict__ Wa2,
    const float* __restrict__ ba2, float* __restrict__ out) {
    int b = blockIdx.x * blockDim.x + threadIdx.x;
    if (b >= NBATCH) return;
    float f0 = 0.f, f1 = 0.f, f2 = 0.f;
    for (int s = 0; s < 8; ++s) {
        int r = b * 8 + s;
        const float* rt = routing + (size_t)r * 6;
#pragma unroll
        for (int e = 0; e < 6; ++e) {
            float wgt = rt[e];
            const float* eop = eo + ((size_t)e * NROWS + r) * 3;
            f0 += wgt * (eop[0] + be3[e * 3 + 0]);
            f1 += wgt * (eop[1] + be3[e * 3 + 1]);
            f2 += wgt * (eop[2] + be3[e * 3 + 2]);
        }
    }
    f0 *= 0.125f; f1 *= 0.125f; f2 *= 0.125f;
    float o0 = ba2[0], o1 = ba2[1], o2 = ba2[2];
#pragma unroll
    for (int h = 0; h < 16; ++h) {
        float a = f0 * Wa1[h] + f1 * Wa1[16 + h] + f2 * Wa1[32 + h] + ba1[h];
        a = fmaxf(a, 0.f);
        o0 += a * Wa2[h * 3 + 0];
        o1 += a * Wa2[h * 3 + 1];
        o2 += a * Wa2[h * 3 + 2];
    }
    out[b * 3 + 0] = o0;
    out[b * 3 + 1] = o1;
    out[b * 3 + 2] = o2;
}

// ---------------- host ----------------

extern "C" void kernel_launch(void* const* d_in, const int* in_sizes, int n_in,
                              void* d_out, int out_size, void* d_ws, size_t ws_size,
                              hipStream_t stream) {
    const float* x   = (const float*)d_in[0];
    const float* Wr1 = (const float*)d_in[1];
    const float* br1 = (const float*)d_in[2];
    const float* Wr2 = (const float*)d_in[3];
    const float* br2 = (const float*)d_in[4];
    const float* We1 = (const float*)d_in[5];
    const float* be1 = (const float*)d_in[6];
    const float* We2 = (const float*)d_in[7];
    const float* be2 = (const float*)d_in[8];
    const float* We3 = (const float*)d_in[9];
    const float* be3 = (const float*)d_in[10];
    const float* Wa1 = (const float*)d_in[11];
    const float* ba1 = (const float*)d_in[12];
    const float* Wa2 = (const float*)d_in[13];
    const float* ba2 = (const float*)d_in[14];
    float* out = (float*)d_out;

    char* ws = (char*)d_ws;
    const size_t off_xbf  = 0;                               // 32768*512*2  = 33554432
    const size_t off_w1t  = off_xbf  + (size_t)33554432;     // 6*1024*512*2 = 6291456
    const size_t off_w2t  = off_w1t  + (size_t)6291456;      // 6*512*1024 fp8 (region 6291456)
    const size_t off_wr1t = off_w2t  + (size_t)6291456;      // 8*32*512*2   = 262144
    const size_t off_rout = off_wr1t + (size_t)262144;       // 32768*6*4    = 786432
    const size_t off_eo   = off_rout + (size_t)786432;       // 6*32768*3*4  = 2359296
    const size_t off_h1   = off_eo   + (size_t)2359296;      // base = 49545216

    // h1 fp8 [32768][6144] = 201.3 MB; total 250.9 MB
    if (off_h1 + (size_t)NROWS * HALL > ws_size) return;  // diagnostic

    bf16*    xbf     = (bf16*)(ws + off_xbf);
    bf16*    W1t     = (bf16*)(ws + off_w1t);
    uint8_t* W2f8t   = (uint8_t*)(ws + off_w2t);
    bf16*    Wr1t    = (bf16*)(ws + off_wr1t);
    float*   routing = (float*)(ws + off_rout);
    float*   eo      = (float*)(ws + off_eo);
    uint8_t* h1      = (uint8_t*)(ws + off_h1);

    // prep
    cvt_bf16_kernel<<<16384, 256, 0, stream>>>(x, xbf, 4194304);
    transpose_cvt<<<dim3(16, 8, 6), 256, 0, stream>>>(We1, W1t, 512, 1024);
    transpose_cvt_fp8<<<dim3(8, 16, 6), 256, 0, stream>>>(We2, W2f8t, 1024, 512, W2SCALE);
    transpose_cvt<<<dim3(1, 8, 8), 256, 0, stream>>>(Wr1, Wr1t, 512, 32);
    zero_f32_kernel<<<2304, 256, 0, stream>>>(eo, 589824);

    // router
    router_kernel<<<dim3(32, 8), 256, 0, stream>>>(xbf, Wr1t, br1, Wr2, br2, routing);

    // experts: gemm1 16-phase ring pipeline (512 thr), gemm2 unchanged
    gemm1_kernel<<<dim3(NROWS / 256, HALL / 256), 512, 0, stream>>>(
        W1t, xbf, be1, h1, HALL);
    gemm2_kernel<<<dim3(NROWS / 128, H2N / 128, NEXP), 256, 0, stream>>>(
        h1, W2f8t, be2, We3, eo, HALL);

    // aggregate
    final_kernel<<<16, 256, 0, stream>>>(routing, eo, be3, Wa1, ba1, Wa2, ba2, out);
}

// Round 4
// 661.491 us; speedup vs baseline: 1.0443x; 1.0443x over previous
//
#include <hip/hip_runtime.h>
#include <cstdint>
#include <cstddef>

typedef __bf16 bf16;
typedef __bf16 bf16x4 __attribute__((ext_vector_type(4)));
typedef __bf16 bf16x8 __attribute__((ext_vector_type(8)));
typedef float  f32x4  __attribute__((ext_vector_type(4)));
typedef long long i64v;

#define NROWS   32768   // 4096 * 8  (X2 rows)
#define DBLK    512
#define H1N     1024
#define H2N     512
#define NEXP    6
#define NBATCH  4096
#define HALL    (NEXP * H1N)   // 6144 h1 cols across all experts
#define W2SCALE 32.0f
#define W2INV   0.03125f

// async global->LDS, 16B per lane; LDS dest = wave-uniform base + lane*16
__device__ __forceinline__ void gld16(const void* g, void* l) {
    __builtin_amdgcn_global_load_lds(
        (const __attribute__((address_space(1))) void*)g,
        (__attribute__((address_space(3))) void*)l, 16, 0, 0);
}

// inf-safe fast tanh: 1 - 2/(exp(2x)+1); exp2+rcp form (3 full-rate + 2 trans)
__device__ __forceinline__ float fast_tanh(float x) {
    float e = __builtin_amdgcn_exp2f(x * 2.8853900817779268f);  // e^{2x}
    float r = __builtin_amdgcn_rcpf(e + 1.0f);
    return __builtin_fmaf(-2.0f, r, 1.0f);
}

__device__ __forceinline__ float hsum16(float v) {
    v += __shfl_xor(v, 1);
    v += __shfl_xor(v, 2);
    v += __shfl_xor(v, 4);
    v += __shfl_xor(v, 8);
    return v;
}

// bf16 tiles: swizzled LDS element offset (16B granule g of row r at g^(r&7))
__device__ __forceinline__ int swz(int row, int g) {
    return row * 64 + ((g ^ (row & 7)) * 8);
}
// fp8 tiles: 64B rows, 4 granules; granule g of row r lives at g^((r>>1)&3)
__device__ __forceinline__ int swz8(int row, int g) {
    return row * 64 + ((g ^ ((row >> 1) & 3)) << 4);
}

// ---------------- prep kernels ----------------

__global__ void cvt_bf16_kernel(const float* __restrict__ in,
                                bf16* __restrict__ out, int n4) {
    int i = blockIdx.x * blockDim.x + threadIdx.x;
    if (i >= n4) return;
    float4 v = ((const float4*)in)[i];
    bf16x4 o;
    o.x = (bf16)v.x; o.y = (bf16)v.y; o.z = (bf16)v.z; o.w = (bf16)v.w;
    ((bf16x4*)out)[i] = o;
}

// in: [E][K][N] f32 -> out: [E][N][K] bf16 (LDS-tiled transpose)
__global__ __launch_bounds__(256) void transpose_cvt(
    const float* __restrict__ in, bf16* __restrict__ out, int K, int N) {
    __shared__ bf16 tile[64][66];
    int e  = blockIdx.z;
    int n0 = blockIdx.x * 64;
    int k0 = blockIdx.y * 64;
    int c  = threadIdx.x & 63;
    int rb = threadIdx.x >> 6;   // 0..3
    const float* src = in + (size_t)e * K * N;
    bf16* dst = out + (size_t)e * N * K;
#pragma unroll
    for (int it = 0; it < 16; ++it) {
        int k = k0 + rb + it * 4;
        int n = n0 + c;
        if (k < K && n < N) tile[rb + it * 4][c] = (bf16)src[(size_t)k * N + n];
    }
    __syncthreads();
#pragma unroll
    for (int it = 0; it < 16; ++it) {
        int n = n0 + rb + it * 4;
        int k = k0 + c;
        if (n < N && k < K) dst[(size_t)n * K + k] = tile[c][rb + it * 4];
    }
}

// in: [E][K][N] f32 -> out: [E][N][K] fp8 e4m3, scaled
__global__ __launch_bounds__(256) void transpose_cvt_fp8(
    const float* __restrict__ in, uint8_t* __restrict__ out, int K, int N,
    float scale) {
    __shared__ float tile[64][65];
    int e  = blockIdx.z;
    int n0 = blockIdx.x * 64;
    int k0 = blockIdx.y * 64;
    int c  = threadIdx.x & 63;
    int rb = threadIdx.x >> 6;   // 0..3
    const float* src = in + (size_t)e * K * N;
    uint8_t* dst = out + (size_t)e * N * K;
#pragma unroll
    for (int it = 0; it < 16; ++it) {
        int k = k0 + rb + it * 4;
        int n = n0 + c;
        if (k < K && n < N) tile[rb + it * 4][c] = src[(size_t)k * N + n];
    }
    __syncthreads();
#pragma unroll
    for (int it = 0; it < 16; ++it) {
        int n = n0 + rb + it * 4;
        int k = k0 + c;
        if (n < N && k < K) {
            float v = tile[c][rb + it * 4] * scale;
            int p = __builtin_amdgcn_cvt_pk_fp8_f32(v, v, 0, false);
            dst[(size_t)n * K + k] = (uint8_t)(p & 0xff);
        }
    }
}

__global__ void zero_f32_kernel(float* __restrict__ p, int n) {
    int i = blockIdx.x * blockDim.x + threadIdx.x;
    if (i < n) p[i] = 0.0f;
}

// ---------------- router ----------------

__global__ __launch_bounds__(256, 2) void router_kernel(
    const bf16* __restrict__ xbf,   // [4096][4096]
    const bf16* __restrict__ Wr1t,  // [8][32][512]
    const float* __restrict__ br1,  // [8][32]
    const float* __restrict__ Wr2,  // [8][32][6]
    const float* __restrict__ br2,  // [8][6]
    float* __restrict__ routing) {  // [32768][6]
    __shared__ __align__(16) bf16 sA[128 * 64];
    __shared__ __align__(16) bf16 sB[32 * 64];
    const int tid = threadIdx.x;
    const int w = tid >> 6, l = tid & 63;
    const int s  = blockIdx.y;
    const int b0 = blockIdx.x * 128;
    const int wm = w * 32;
    const int srow = l >> 3, schk = (l & 7) * 8;
    const int fr = l & 15, fq = l >> 4;
    const bf16* Ab = xbf + (size_t)s * 512;
    const bf16* Bb = Wr1t + (size_t)s * (32 * 512);

    f32x4 acc[2][2];
#pragma unroll
    for (int i = 0; i < 2; ++i)
#pragma unroll
        for (int j = 0; j < 2; ++j) acc[i][j] = (f32x4){0.f, 0.f, 0.f, 0.f};

    for (int k0 = 0; k0 < 512; k0 += 64) {
        __syncthreads();
#pragma unroll
        for (int jj = 0; jj < 4; ++jj) {
            int row = w * 32 + jj * 8;
            gld16(Ab + (size_t)(b0 + row + srow) * 4096 + k0 + schk, sA + row * 64);
        }
        gld16(Bb + (size_t)(w * 8 + srow) * 512 + k0 + schk, sB + w * 8 * 64);
        __syncthreads();
#pragma unroll
        for (int ks = 0; ks < 2; ++ks) {
            bf16x8 af[2], bfr[2];
#pragma unroll
            for (int i = 0; i < 2; ++i)
                af[i] = *(const bf16x8*)&sA[(wm + i * 16 + fr) * 64 + ks * 32 + fq * 8];
#pragma unroll
            for (int j = 0; j < 2; ++j)
                bfr[j] = *(const bf16x8*)&sB[(j * 16 + fr) * 64 + ks * 32 + fq * 8];
#pragma unroll
            for (int i = 0; i < 2; ++i)
#pragma unroll
                for (int j = 0; j < 2; ++j)
                    acc[i][j] = __builtin_amdgcn_mfma_f32_16x16x32_bf16(
                        af[i], bfr[j], acc[i][j], 0, 0, 0);
        }
    }

    float b1v[2], w2v[2][6], br2v[6];
#pragma unroll
    for (int j = 0; j < 2; ++j) {
        int col = j * 16 + fr;
        b1v[j] = br1[s * 32 + col];
#pragma unroll
        for (int e2 = 0; e2 < 6; ++e2) w2v[j][e2] = Wr2[(s * 32 + col) * 6 + e2];
    }
#pragma unroll
    for (int e2 = 0; e2 < 6; ++e2) br2v[e2] = br2[s * 6 + e2];

#pragma unroll
    for (int i = 0; i < 2; ++i) {
#pragma unroll
        for (int r = 0; r < 4; ++r) {
            float lg[6] = {0.f, 0.f, 0.f, 0.f, 0.f, 0.f};
#pragma unroll
            for (int j = 0; j < 2; ++j) {
                float t = fmaxf(acc[i][j][r] + b1v[j], 0.f);
#pragma unroll
                for (int e2 = 0; e2 < 6; ++e2) lg[e2] += t * w2v[j][e2];
            }
#pragma unroll
            for (int e2 = 0; e2 < 6; ++e2) lg[e2] = hsum16(lg[e2]) + br2v[e2];
            float mx = lg[0];
#pragma unroll
            for (int e2 = 1; e2 < 6; ++e2) mx = fmaxf(mx, lg[e2]);
            float p[6], sum = 0.f;
#pragma unroll
            for (int e2 = 0; e2 < 6; ++e2) { p[e2] = __expf(lg[e2] - mx); sum += p[e2]; }
            float inv = __fdividef(1.f, sum);
            if (fr == 0) {
                int brow = b0 + wm + i * 16 + fq * 4 + r;
                float* dst = routing + ((size_t)brow * 8 + s) * 6;
#pragma unroll
                for (int e2 = 0; e2 < 6; ++e2) dst[e2] = p[e2] * inv;
            }
        }
    }
}

// ------- expert layer 1: h1[xrow][col] = fp8(tanh(W1t@X^T+b)) -------
// R4 == R3 (container-level failure last round, kernel re-audited clean):
// register-staged double-buffered pipeline (T14). 256x256 tile, 512
// threads (8 waves 2m x 4n), BK=64. Staging = global_load_dwordx4 -> VGPR
// (2 K-tiles deep = 256B in flight per thread = 128KB/CU) -> ds_write_b128.
// Compiler's counted per-use vmcnt replaces manual waits; raw s_barrier
// (never __syncthreads: its vmcnt(0) drain would kill in-flight loads).
// All reg arrays macro-expanded with static indices (no scratch).
__global__ __launch_bounds__(512, 2) void gemm1_kernel(
    const bf16* __restrict__ A,     // [6144][512] (W1t, all experts)
    const bf16* __restrict__ B,     // xbf [32768][512]
    const float* __restrict__ bias, // [6144]
    uint8_t* __restrict__ h1,       // [32768][6144] fp8
    int ldh) {
    __shared__ __align__(16) bf16 sA[2][256 * 64];   // 2 x 32 KB
    __shared__ __align__(16) bf16 sB[2][256 * 64];   // 2 x 32 KB
    const int tid = threadIdx.x;
    const int w = tid >> 6, l = tid & 63;
    const int n0 = blockIdx.x * 256;   // xrows (x-fastest: A-panel hot in L2)
    const int m0 = blockIdx.y * 256;   // h1 cols
    const int wm = (w & 1) * 128;      // 2 wave-cols in m
    const int wn = (w >> 1) * 64;      // 4 wave-rows in n
    const int fr = l & 15, fq = l >> 4;

    // staging map: lane covers row rbase=w*32+(l>>3) (+q*8), granule gg=l&7.
    // global read is coalesced (8 rows x 128B per instr); ds_write goes to
    // the swizzled slot gg^(row&7) = gg^(l>>3)  (row&7 == l>>3).
    const int rbase = w * 32 + (l >> 3);
    const int gg = l & 7;
    const bf16* Ag = A + (size_t)(m0 + rbase) * DBLK + gg * 8;
    const bf16* Bg = B + (size_t)(n0 + rbase) * DBLK + gg * 8;
    const int woff = rbase * 64 + ((gg ^ (l >> 3)) * 8);

    f32x4 acc[8][4];
#pragma unroll
    for (int i = 0; i < 8; ++i)
#pragma unroll
        for (int j = 0; j < 4; ++j) acc[i][j] = (f32x4){0.f, 0.f, 0.f, 0.f};

#define G1_LOAD(SA_, SB_, T_)                                              \
    {                                                                      \
        _Pragma("unroll") for (int q = 0; q < 4; ++q) {                    \
            SA_[q] = *(const bf16x8*)(Ag + (size_t)q * 4096 + (T_) * 64);  \
            SB_[q] = *(const bf16x8*)(Bg + (size_t)q * 4096 + (T_) * 64);  \
        }                                                                  \
    }
#define G1_WRITE(SA_, SB_, BUF_)                                           \
    {                                                                      \
        _Pragma("unroll") for (int q = 0; q < 4; ++q) {                    \
            *(bf16x8*)&sA[BUF_][woff + q * 512] = SA_[q];                  \
            *(bf16x8*)&sB[BUF_][woff + q * 512] = SB_[q];                  \
        }                                                                  \
    }
#define G1_COMP(BUF_)                                                      \
    {                                                                      \
        _Pragma("unroll") for (int ks = 0; ks < 2; ++ks) {                 \
            bf16x8 af[8], bfr[4];                                          \
            _Pragma("unroll") for (int i = 0; i < 8; ++i)                  \
                af[i] = *(const bf16x8*)&sA[BUF_][swz(wm + i * 16 + fr,    \
                                                      ks * 4 + fq)];       \
            _Pragma("unroll") for (int j = 0; j < 4; ++j)                  \
                bfr[j] = *(const bf16x8*)&sB[BUF_][swz(wn + j * 16 + fr,   \
                                                       ks * 4 + fq)];      \
            __builtin_amdgcn_s_setprio(1);                                 \
            _Pragma("unroll") for (int i = 0; i < 8; ++i)                  \
                _Pragma("unroll") for (int j = 0; j < 4; ++j)              \
                    acc[i][j] = __builtin_amdgcn_mfma_f32_16x16x32_bf16(   \
                        af[i], bfr[j], acc[i][j], 0, 0, 0);                \
            __builtin_amdgcn_s_setprio(0);                                 \
        }                                                                  \
    }
#define G1_BAR()                                                           \
    asm volatile("s_waitcnt lgkmcnt(0)" ::: "memory");                     \
    __builtin_amdgcn_s_barrier();                                          \
    __builtin_amdgcn_sched_barrier(0);

    bf16x8 S0A[4], S0B[4], S1A[4], S1B[4];
    // prologue: tiles 0,1 -> regs; tile 0 -> LDS buf0
    G1_LOAD(S0A, S0B, 0)
    G1_LOAD(S1A, S1B, 1)
    G1_WRITE(S0A, S0B, 0)
    G1_BAR()
    // t=0..7: compute tile t from buf[t&1]; write tile t+1; load tile t+2
    G1_LOAD(S0A, S0B, 2) G1_WRITE(S1A, S1B, 1) G1_COMP(0) G1_BAR()
    G1_LOAD(S1A, S1B, 3) G1_WRITE(S0A, S0B, 0) G1_COMP(1) G1_BAR()
    G1_LOAD(S0A, S0B, 4) G1_WRITE(S1A, S1B, 1) G1_COMP(0) G1_BAR()
    G1_LOAD(S1A, S1B, 5) G1_WRITE(S0A, S0B, 0) G1_COMP(1) G1_BAR()
    G1_LOAD(S0A, S0B, 6) G1_WRITE(S1A, S1B, 1) G1_COMP(0) G1_BAR()
    G1_LOAD(S1A, S1B, 7) G1_WRITE(S0A, S0B, 0) G1_COMP(1) G1_BAR()
    G1_WRITE(S1A, S1B, 1) G1_COMP(0) G1_BAR()
    G1_COMP(1)

#undef G1_LOAD
#undef G1_WRITE
#undef G1_COMP
#undef G1_BAR

    // epilogue: j-outer / i-inner so each 64B h1 line is completed by 4
    // back-to-back 16B bursts (kills partial-line write amplification)
    float4 bb[8];
#pragma unroll
    for (int i = 0; i < 8; ++i)
        bb[i] = *(const float4*)&bias[m0 + wm + i * 16 + fq * 4];
#pragma unroll
    for (int j = 0; j < 4; ++j) {
        int xrow = n0 + wn + j * 16 + fr;
        uint8_t* dst = &h1[(size_t)xrow * ldh + m0 + wm + fq * 4];
#pragma unroll
        for (int i = 0; i < 8; ++i) {
            float t0 = fast_tanh(acc[i][j][0] + bb[i].x);
            float t1 = fast_tanh(acc[i][j][1] + bb[i].y);
            float t2 = fast_tanh(acc[i][j][2] + bb[i].z);
            float t3 = fast_tanh(acc[i][j][3] + bb[i].w);
            int p = 0;
            p = __builtin_amdgcn_cvt_pk_fp8_f32(t0, t1, p, false);
            p = __builtin_amdgcn_cvt_pk_fp8_f32(t2, t3, p, true);
            *(uint32_t*)(dst + i * 16) = (uint32_t)p;
        }
    }
}

// ------- layer 2+3 (fp8 x fp8): eo += tanh(h1@W2+b)@We3 -------
// A = W2f8t rows (h2 cols, x32-scaled), B = h1 rows (fp8, col band e*1024).
__global__ __launch_bounds__(256, 4) void gemm2_kernel(
    const uint8_t* __restrict__ h1,    // [32768][6144] fp8
    const uint8_t* __restrict__ W2f8t, // [6][512][1024] fp8 (x32)
    const float* __restrict__ be2,     // [6][512]
    const float* __restrict__ We3,     // [6][512][3]
    float* __restrict__ eo,            // [6][32768][3]
    int ldh) {
    __shared__ __align__(16) uint8_t sA[128 * 64];
    __shared__ __align__(16) uint8_t sB[128 * 64];
    __shared__ float w3s[128 * 3];
    __shared__ float b2s[128];
    const int tid = threadIdx.x;
    const int w = tid >> 6, l = tid & 63;
    const int e  = blockIdx.z;
    const int n0 = blockIdx.x * 128;   // xrows
    const int m0 = blockIdx.y * 128;   // h2 cols (0..511)
    const int wm = (w & 1) * 64, wn = (w >> 1) * 64;
    const int srow4 = l >> 2;                         // dest row within 16-row group
    const int g4 = (((l & 3) ^ ((l >> 3) & 3)) << 4); // source granule (matches swz8)
    const int fr = l & 15, fq = l >> 4;
    const uint8_t* Ae = W2f8t + (size_t)e * (H2N * H1N);
    const uint8_t* Be = h1 + (size_t)e * H1N;   // column band within ldh=6144

    if (tid < 128) {
        int c = m0 + tid;
        b2s[tid] = be2[e * H2N + c];
        w3s[tid * 3 + 0] = We3[((size_t)e * H2N + c) * 3 + 0];
        w3s[tid * 3 + 1] = We3[((size_t)e * H2N + c) * 3 + 1];
        w3s[tid * 3 + 2] = We3[((size_t)e * H2N + c) * 3 + 2];
    }

    f32x4 acc[4][4];
#pragma unroll
    for (int i = 0; i < 4; ++i)
#pragma unroll
        for (int j = 0; j < 4; ++j) acc[i][j] = (f32x4){0.f, 0.f, 0.f, 0.f};

    for (int k0 = 0; k0 < H1N; k0 += 64) {
        __syncthreads();
#pragma unroll
        for (int jj = 0; jj < 2; ++jj) {
            int row = w * 32 + jj * 16 + srow4;
            gld16(Ae + (size_t)(m0 + row) * H1N + k0 + g4, sA + (w * 32 + jj * 16) * 64);
            gld16(Be + (size_t)(n0 + row) * ldh + k0 + g4, sB + (w * 32 + jj * 16) * 64);
        }
        __syncthreads();
#pragma unroll
        for (int ks = 0; ks < 2; ++ks) {
            i64v af[4], bfr[4];
#pragma unroll
            for (int i = 0; i < 4; ++i) {
                int row = wm + i * 16 + fr;
                af[i] = *(const i64v*)&sA[swz8(row, ks * 2 + (fq >> 1)) + ((fq & 1) << 3)];
            }
#pragma unroll
            for (int j = 0; j < 4; ++j) {
                int row = wn + j * 16 + fr;
                bfr[j] = *(const i64v*)&sB[swz8(row, ks * 2 + (fq >> 1)) + ((fq & 1) << 3)];
            }
#pragma unroll
            for (int i = 0; i < 4; ++i)
#pragma unroll
                for (int j = 0; j < 4; ++j)
                    acc[i][j] = __builtin_amdgcn_mfma_f32_16x16x32_fp8_fp8(
                        af[i], bfr[j], acc[i][j], 0, 0, 0);
        }
    }

    // lane holds 16 h2-cols of xrow; layer-3 col-sum in-register; acc is x32-scaled
    float p[4][3];
#pragma unroll
    for (int j = 0; j < 4; ++j) { p[j][0] = 0.f; p[j][1] = 0.f; p[j][2] = 0.f; }
#pragma unroll
    for (int i = 0; i < 4; ++i) {
        int cl = wm + i * 16 + fq * 4;   // local col 0..127
        float4 bb = *(const float4*)&b2s[cl];
        float4 wa = *(const float4*)&w3s[cl * 3 + 0];
        float4 wb = *(const float4*)&w3s[cl * 3 + 4];
        float4 wc = *(const float4*)&w3s[cl * 3 + 8];
        float bias4[4] = {bb.x, bb.y, bb.z, bb.w};
        float w30[4] = {wa.x, wa.w, wb.z, wc.y};
        float w31[4] = {wa.y, wb.x, wb.w, wc.z};
        float w32[4] = {wa.z, wb.y, wc.x, wc.w};
#pragma unroll
        for (int j = 0; j < 4; ++j) {
#pragma unroll
            for (int r = 0; r < 4; ++r) {
                float t = fast_tanh(acc[i][j][r] * W2INV + bias4[r]);
                p[j][0] += t * w30[r];
                p[j][1] += t * w31[r];
                p[j][2] += t * w32[r];
            }
        }
    }
#pragma unroll
    for (int j = 0; j < 4; ++j) {
        float v0 = p[j][0], v1 = p[j][1], v2 = p[j][2];
        v0 += __shfl_xor(v0, 16); v0 += __shfl_xor(v0, 32);
        v1 += __shfl_xor(v1, 16); v1 += __shfl_xor(v1, 32);
        v2 += __shfl_xor(v2, 16); v2 += __shfl_xor(v2, 32);
        if (fq == 0) {
            int xrow = n0 + wn + j * 16 + fr;
            float* dst = eo + ((size_t)e * NROWS + xrow) * 3;
            atomicAdd(dst + 0, v0);
            atomicAdd(dst + 1, v1);
            atomicAdd(dst + 2, v2);
        }
    }
}

// ---------------- final: routing-weighted mean + aggregator MLP ----------------
__global__ void final_kernel(
    const float* __restrict__ routing, const float* __restrict__ eo,
    const float* __restrict__ be3, const float* __restrict__ Wa1,
    const float* __restrict__ ba1, const float* __restrict__ Wa2,
    const float* __restrict__ ba2, float* __restrict__ out) {
    int b = blockIdx.x * blockDim.x + threadIdx.x;
    if (b >= NBATCH) return;
    float f0 = 0.f, f1 = 0.f, f2 = 0.f;
    for (int s = 0; s < 8; ++s) {
        int r = b * 8 + s;
        const float* rt = routing + (size_t)r * 6;
#pragma unroll
        for (int e = 0; e < 6; ++e) {
            float wgt = rt[e];
            const float* eop = eo + ((size_t)e * NROWS + r) * 3;
            f0 += wgt * (eop[0] + be3[e * 3 + 0]);
            f1 += wgt * (eop[1] + be3[e * 3 + 1]);
            f2 += wgt * (eop[2] + be3[e * 3 + 2]);
        }
    }
    f0 *= 0.125f; f1 *= 0.125f; f2 *= 0.125f;
    float o0 = ba2[0], o1 = ba2[1], o2 = ba2[2];
#pragma unroll
    for (int h = 0; h < 16; ++h) {
        float a = f0 * Wa1[h] + f1 * Wa1[16 + h] + f2 * Wa1[32 + h] + ba1[h];
        a = fmaxf(a, 0.f);
        o0 += a * Wa2[h * 3 + 0];
        o1 += a * Wa2[h * 3 + 1];
        o2 += a * Wa2[h * 3 + 2];
    }
    out[b * 3 + 0] = o0;
    out[b * 3 + 1] = o1;
    out[b * 3 + 2] = o2;
}

// ---------------- host ----------------

extern "C" void kernel_launch(void* const* d_in, const int* in_sizes, int n_in,
                              void* d_out, int out_size, void* d_ws, size_t ws_size,
                              hipStream_t stream) {
    const float* x   = (const float*)d_in[0];
    const float* Wr1 = (const float*)d_in[1];
    const float* br1 = (const float*)d_in[2];
    const float* Wr2 = (const float*)d_in[3];
    const float* br2 = (const float*)d_in[4];
    const float* We1 = (const float*)d_in[5];
    const float* be1 = (const float*)d_in[6];
    const float* We2 = (const float*)d_in[7];
    const float* be2 = (const float*)d_in[8];
    const float* We3 = (const float*)d_in[9];
    const float* be3 = (const float*)d_in[10];
    const float* Wa1 = (const float*)d_in[11];
    const float* ba1 = (const float*)d_in[12];
    const float* Wa2 = (const float*)d_in[13];
    const float* ba2 = (const float*)d_in[14];
    float* out = (float*)d_out;

    char* ws = (char*)d_ws;
    const size_t off_xbf  = 0;                               // 32768*512*2  = 33554432
    const size_t off_w1t  = off_xbf  + (size_t)33554432;     // 6*1024*512*2 = 6291456
    const size_t off_w2t  = off_w1t  + (size_t)6291456;      // 6*512*1024 fp8 (region 6291456)
    const size_t off_wr1t = off_w2t  + (size_t)6291456;      // 8*32*512*2   = 262144
    const size_t off_rout = off_wr1t + (size_t)262144;       // 32768*6*4    = 786432
    const size_t off_eo   = off_rout + (size_t)786432;       // 6*32768*3*4  = 2359296
    const size_t off_h1   = off_eo   + (size_t)2359296;      // base = 49545216

    // h1 fp8 [32768][6144] = 201.3 MB; total 250.9 MB
    if (off_h1 + (size_t)NROWS * HALL > ws_size) return;  // diagnostic

    bf16*    xbf     = (bf16*)(ws + off_xbf);
    bf16*    W1t     = (bf16*)(ws + off_w1t);
    uint8_t* W2f8t   = (uint8_t*)(ws + off_w2t);
    bf16*    Wr1t    = (bf16*)(ws + off_wr1t);
    float*   routing = (float*)(ws + off_rout);
    float*   eo      = (float*)(ws + off_eo);
    uint8_t* h1      = (uint8_t*)(ws + off_h1);

    // prep
    cvt_bf16_kernel<<<16384, 256, 0, stream>>>(x, xbf, 4194304);
    transpose_cvt<<<dim3(16, 8, 6), 256, 0, stream>>>(We1, W1t, 512, 1024);
    transpose_cvt_fp8<<<dim3(8, 16, 6), 256, 0, stream>>>(We2, W2f8t, 1024, 512, W2SCALE);
    transpose_cvt<<<dim3(1, 8, 8), 256, 0, stream>>>(Wr1, Wr1t, 512, 32);
    zero_f32_kernel<<<2304, 256, 0, stream>>>(eo, 589824);

    // router
    router_kernel<<<dim3(32, 8), 256, 0, stream>>>(xbf, Wr1t, br1, Wr2, br2, routing);

    // experts: gemm1 reg-staged pipeline (512 thr), gemm2 unchanged
    gemm1_kernel<<<dim3(NROWS / 256, HALL / 256), 512, 0, stream>>>(
        W1t, xbf, be1, h1, HALL);
    gemm2_kernel<<<dim3(NROWS / 128, H2N / 128, NEXP), 256, 0, stream>>>(
        h1, W2f8t, be2, We3, eo, HALL);

    // aggregate
    final_kernel<<<16, 256, 0, stream>>>(routing, eo, be3, Wa1, ba1, Wa2, ba2, out);
}

// Round 6
// 657.255 us; speedup vs baseline: 1.0510x; 1.0064x over previous
//
#include <hip/hip_runtime.h>
#include <cstdint>
#include <cstddef>

typedef __bf16 bf16;
typedef __bf16 bf16x4 __attribute__((ext_vector_type(4)));
typedef __bf16 bf16x8 __attribute__((ext_vector_type(8)));
typedef float  f32x4  __attribute__((ext_vector_type(4)));
typedef long long i64v;

#define NROWS   32768   // 4096 * 8  (X2 rows)
#define DBLK    512
#define H1N     1024
#define H2N     512
#define NEXP    6
#define NBATCH  4096
#define HALL    (NEXP * H1N)   // 6144 h1 cols across all experts
#define W2SCALE 32.0f
#define W2INV   0.03125f

// async global->LDS, 16B per lane; LDS dest = wave-uniform base + lane*16
__device__ __forceinline__ void gld16(const void* g, void* l) {
    __builtin_amdgcn_global_load_lds(
        (const __attribute__((address_space(1))) void*)g,
        (__attribute__((address_space(3))) void*)l, 16, 0, 0);
}

// inf-safe fast tanh: 1 - 2/(exp(2x)+1); exp2+rcp form
__device__ __forceinline__ float fast_tanh(float x) {
    float e = __builtin_amdgcn_exp2f(x * 2.8853900817779268f);  // e^{2x}
    float r = __builtin_amdgcn_rcpf(e + 1.0f);
    return __builtin_fmaf(-2.0f, r, 1.0f);
}

__device__ __forceinline__ float hsum16(float v) {
    v += __shfl_xor(v, 1);
    v += __shfl_xor(v, 2);
    v += __shfl_xor(v, 4);
    v += __shfl_xor(v, 8);
    return v;
}

// bf16 tiles: swizzled LDS element offset (16B granule g of row r at g^(r&7))
__device__ __forceinline__ int swz(int row, int g) {
    return row * 64 + ((g ^ (row & 7)) * 8);
}
// fp8 tiles: 64B rows, 4 granules; granule g of row r lives at g^((r>>1)&3)
__device__ __forceinline__ int swz8(int row, int g) {
    return row * 64 + ((g ^ ((row >> 1) & 3)) << 4);
}

// ---------------- prep kernels ----------------

__global__ void cvt_bf16_kernel(const float* __restrict__ in,
                                bf16* __restrict__ out, int n4) {
    int i = blockIdx.x * blockDim.x + threadIdx.x;
    if (i >= n4) return;
    float4 v = ((const float4*)in)[i];
    bf16x4 o;
    o.x = (bf16)v.x; o.y = (bf16)v.y; o.z = (bf16)v.z; o.w = (bf16)v.w;
    ((bf16x4*)out)[i] = o;
}

// in: [E][K][N] f32 -> out: [E][N][K] bf16 (LDS-tiled transpose)
__global__ __launch_bounds__(256) void transpose_cvt(
    const float* __restrict__ in, bf16* __restrict__ out, int K, int N) {
    __shared__ bf16 tile[64][66];
    int e  = blockIdx.z;
    int n0 = blockIdx.x * 64;
    int k0 = blockIdx.y * 64;
    int c  = threadIdx.x & 63;
    int rb = threadIdx.x >> 6;   // 0..3
    const float* src = in + (size_t)e * K * N;
    bf16* dst = out + (size_t)e * N * K;
#pragma unroll
    for (int it = 0; it < 16; ++it) {
        int k = k0 + rb + it * 4;
        int n = n0 + c;
        if (k < K && n < N) tile[rb + it * 4][c] = (bf16)src[(size_t)k * N + n];
    }
    __syncthreads();
#pragma unroll
    for (int it = 0; it < 16; ++it) {
        int n = n0 + rb + it * 4;
        int k = k0 + c;
        if (n < N && k < K) dst[(size_t)n * K + k] = tile[c][rb + it * 4];
    }
}

// in: [E][K][N] f32 -> out: [E][N][K] fp8 e4m3, scaled
__global__ __launch_bounds__(256) void transpose_cvt_fp8(
    const float* __restrict__ in, uint8_t* __restrict__ out, int K, int N,
    float scale) {
    __shared__ float tile[64][65];
    int e  = blockIdx.z;
    int n0 = blockIdx.x * 64;
    int k0 = blockIdx.y * 64;
    int c  = threadIdx.x & 63;
    int rb = threadIdx.x >> 6;   // 0..3
    const float* src = in + (size_t)e * K * N;
    uint8_t* dst = out + (size_t)e * N * K;
#pragma unroll
    for (int it = 0; it < 16; ++it) {
        int k = k0 + rb + it * 4;
        int n = n0 + c;
        if (k < K && n < N) tile[rb + it * 4][c] = src[(size_t)k * N + n];
    }
    __syncthreads();
#pragma unroll
    for (int it = 0; it < 16; ++it) {
        int n = n0 + rb + it * 4;
        int k = k0 + c;
        if (n < N && k < K) {
            float v = tile[c][rb + it * 4] * scale;
            int p = __builtin_amdgcn_cvt_pk_fp8_f32(v, v, 0, false);
            dst[(size_t)n * K + k] = (uint8_t)(p & 0xff);
        }
    }
}

__global__ void zero_f32_kernel(float* __restrict__ p, int n) {
    int i = blockIdx.x * blockDim.x + threadIdx.x;
    if (i < n) p[i] = 0.0f;
}

// ---------------- router ----------------

__global__ __launch_bounds__(256, 2) void router_kernel(
    const bf16* __restrict__ xbf,   // [4096][4096]
    const bf16* __restrict__ Wr1t,  // [8][32][512]
    const float* __restrict__ br1,  // [8][32]
    const float* __restrict__ Wr2,  // [8][32][6]
    const float* __restrict__ br2,  // [8][6]
    float* __restrict__ routing) {  // [32768][6]
    __shared__ __align__(16) bf16 sA[128 * 64];
    __shared__ __align__(16) bf16 sB[32 * 64];
    const int tid = threadIdx.x;
    const int w = tid >> 6, l = tid & 63;
    const int s  = blockIdx.y;
    const int b0 = blockIdx.x * 128;
    const int wm = w * 32;
    const int srow = l >> 3, schk = (l & 7) * 8;
    const int fr = l & 15, fq = l >> 4;
    const bf16* Ab = xbf + (size_t)s * 512;
    const bf16* Bb = Wr1t + (size_t)s * (32 * 512);

    f32x4 acc[2][2];
#pragma unroll
    for (int i = 0; i < 2; ++i)
#pragma unroll
        for (int j = 0; j < 2; ++j) acc[i][j] = (f32x4){0.f, 0.f, 0.f, 0.f};

    for (int k0 = 0; k0 < 512; k0 += 64) {
        __syncthreads();
#pragma unroll
        for (int jj = 0; jj < 4; ++jj) {
            int row = w * 32 + jj * 8;
            gld16(Ab + (size_t)(b0 + row + srow) * 4096 + k0 + schk, sA + row * 64);
        }
        gld16(Bb + (size_t)(w * 8 + srow) * 512 + k0 + schk, sB + w * 8 * 64);
        __syncthreads();
#pragma unroll
        for (int ks = 0; ks < 2; ++ks) {
            bf16x8 af[2], bfr[2];
#pragma unroll
            for (int i = 0; i < 2; ++i)
                af[i] = *(const bf16x8*)&sA[(wm + i * 16 + fr) * 64 + ks * 32 + fq * 8];
#pragma unroll
            for (int j = 0; j < 2; ++j)
                bfr[j] = *(const bf16x8*)&sB[(j * 16 + fr) * 64 + ks * 32 + fq * 8];
#pragma unroll
            for (int i = 0; i < 2; ++i)
#pragma unroll
                for (int j = 0; j < 2; ++j)
                    acc[i][j] = __builtin_amdgcn_mfma_f32_16x16x32_bf16(
                        af[i], bfr[j], acc[i][j], 0, 0, 0);
        }
    }

    float b1v[2], w2v[2][6], br2v[6];
#pragma unroll
    for (int j = 0; j < 2; ++j) {
        int col = j * 16 + fr;
        b1v[j] = br1[s * 32 + col];
#pragma unroll
        for (int e2 = 0; e2 < 6; ++e2) w2v[j][e2] = Wr2[(s * 32 + col) * 6 + e2];
    }
#pragma unroll
    for (int e2 = 0; e2 < 6; ++e2) br2v[e2] = br2[s * 6 + e2];

#pragma unroll
    for (int i = 0; i < 2; ++i) {
#pragma unroll
        for (int r = 0; r < 4; ++r) {
            float lg[6] = {0.f, 0.f, 0.f, 0.f, 0.f, 0.f};
#pragma unroll
            for (int j = 0; j < 2; ++j) {
                float t = fmaxf(acc[i][j][r] + b1v[j], 0.f);
#pragma unroll
                for (int e2 = 0; e2 < 6; ++e2) lg[e2] += t * w2v[j][e2];
            }
#pragma unroll
            for (int e2 = 0; e2 < 6; ++e2) lg[e2] = hsum16(lg[e2]) + br2v[e2];
            float mx = lg[0];
#pragma unroll
            for (int e2 = 1; e2 < 6; ++e2) mx = fmaxf(mx, lg[e2]);
            float p[6], sum = 0.f;
#pragma unroll
            for (int e2 = 0; e2 < 6; ++e2) { p[e2] = __expf(lg[e2] - mx); sum += p[e2]; }
            float inv = __fdividef(1.f, sum);
            if (fr == 0) {
                int brow = b0 + wm + i * 16 + fq * 4 + r;
                float* dst = routing + ((size_t)brow * 8 + s) * 6;
#pragma unroll
                for (int e2 = 0; e2 < 6; ++e2) dst[e2] = p[e2] * inv;
            }
        }
    }
}

// ------- expert layer 1: h1[xrow][col] = fp8(tanh(W1t@X^T+b)) -------
// R6 == R5's gemm1 (audited race-free; isolating it this round).
// 8-phase fine-interleaved pipeline: 256x256 tile, 512 thr (8 waves
// 2m x 4n), BK=64, K=512 -> 8 tiles x 4 phases. Per phase: {stage issue |
// ds_read | lgkmcnt(0) | setprio(1) 16 MFMA setprio(0) | barrier}.
// Wave reads its A-half EVERY phase but its B-quarter only at phase 0 ->
// stage tile t+1's A at t.p0, tile t+2's B at t.p1 into the just-freed
// current B buffer. One counted vmcnt(4) per tile at p3 (retires A(t+1),
// B(t+1); leaves B(t+2) in flight); never drains mid-loop.
__global__ __launch_bounds__(512, 2) void gemm1_kernel(
    const bf16* __restrict__ A,     // [6144][512] (W1t, all experts)
    const bf16* __restrict__ B,     // xbf [32768][512]
    const float* __restrict__ bias, // [6144]
    uint8_t* __restrict__ h1,       // [32768][6144] fp8
    int ldh) {
    __shared__ __align__(16) bf16 sA[2][256 * 64];   // 2 x 32 KB
    __shared__ __align__(16) bf16 sB[2][256 * 64];   // 2 x 32 KB
    const int tid = threadIdx.x;
    const int w = tid >> 6, l = tid & 63;
    const int n0 = blockIdx.x * 256;   // xrows (x-fastest: A-panel hot in L2)
    const int m0 = blockIdx.y * 256;   // h1 cols
    const int wm = (w & 1) * 128;      // 2 wave-cols in m
    const int wn = (w >> 1) * 64;      // 4 wave-rows in n
    const int fr = l & 15, fq = l >> 4;

    // staging: lane covers row w*32+q*8+(l>>3), dest granule l&7 (linear),
    // source granule pre-swizzled (l&7)^(l>>3)  (row&7 == l>>3)
    const int srow = l >> 3;
    const int gg = l & 7;
    const bf16* Ag = A + (size_t)(m0 + w * 32 + srow) * DBLK + ((gg ^ srow) * 8);
    const bf16* Bg = B + (size_t)(n0 + w * 32 + srow) * DBLK + ((gg ^ srow) * 8);

    f32x4 acc[8][4];
#pragma unroll
    for (int i = 0; i < 8; ++i)
#pragma unroll
        for (int j = 0; j < 4; ++j) acc[i][j] = (f32x4){0.f, 0.f, 0.f, 0.f};

    bf16x8 bfr[4][2];

    // prologue: A0 -> sA[0], B0 -> sB[0], B1 -> sB[1]
#pragma unroll
    for (int q = 0; q < 4; ++q) {
        gld16(Ag + (size_t)q * 8 * DBLK, &sA[0][(w * 32 + q * 8) * 64]);
        gld16(Bg + (size_t)q * 8 * DBLK, &sB[0][(w * 32 + q * 8) * 64]);
        gld16(Bg + (size_t)q * 8 * DBLK + 64, &sB[1][(w * 32 + q * 8) * 64]);
    }
    asm volatile("s_waitcnt vmcnt(0)" ::: "memory");
    __builtin_amdgcn_s_barrier();
    __builtin_amdgcn_sched_barrier(0);

#define G1_PHASE(TAU, P)                                                      \
    {                                                                         \
        constexpr int CUR_ = (TAU) & 1;                                       \
        if constexpr ((P) == 0 && (TAU) < 7) {                                \
            _Pragma("unroll") for (int q = 0; q < 4; ++q)                     \
                gld16(Ag + (size_t)q * 8 * DBLK + ((TAU) + 1) * 64,           \
                      &sA[1 - CUR_][(w * 32 + q * 8) * 64]);                  \
        }                                                                     \
        if constexpr ((P) == 1 && (TAU) < 6) {                                \
            _Pragma("unroll") for (int q = 0; q < 4; ++q)                     \
                gld16(Bg + (size_t)q * 8 * DBLK + ((TAU) + 2) * 64,           \
                      &sB[CUR_][(w * 32 + q * 8) * 64]);                      \
        }                                                                     \
        if constexpr ((P) == 0) {                                             \
            _Pragma("unroll") for (int j = 0; j < 4; ++j)                     \
                _Pragma("unroll") for (int ks = 0; ks < 2; ++ks)              \
                    bfr[j][ks] = *(const bf16x8*)&sB[CUR_][                   \
                        swz(wn + j * 16 + fr, ks * 4 + fq)];                  \
        }                                                                     \
        bf16x8 af0 = *(const bf16x8*)&sA[CUR_][swz(wm + (P)*32 + fr, fq)];    \
        bf16x8 af1 = *(const bf16x8*)&sA[CUR_][swz(wm + (P)*32 + fr, 4 + fq)];\
        bf16x8 af2 = *(const bf16x8*)&sA[CUR_][swz(wm + (P)*32 + 16 + fr, fq)];\
        bf16x8 af3 = *(const bf16x8*)&sA[CUR_][swz(wm + (P)*32 + 16 + fr, 4 + fq)];\
        asm volatile("s_waitcnt lgkmcnt(0)" ::: "memory");                    \
        __builtin_amdgcn_sched_barrier(0);                                    \
        __builtin_amdgcn_s_setprio(1);                                        \
        _Pragma("unroll") for (int j = 0; j < 4; ++j) {                       \
            acc[(P)*2][j] = __builtin_amdgcn_mfma_f32_16x16x32_bf16(          \
                af0, bfr[j][0], acc[(P)*2][j], 0, 0, 0);                      \
            acc[(P)*2][j] = __builtin_amdgcn_mfma_f32_16x16x32_bf16(          \
                af1, bfr[j][1], acc[(P)*2][j], 0, 0, 0);                      \
            acc[(P)*2 + 1][j] = __builtin_amdgcn_mfma_f32_16x16x32_bf16(      \
                af2, bfr[j][0], acc[(P)*2 + 1][j], 0, 0, 0);                  \
            acc[(P)*2 + 1][j] = __builtin_amdgcn_mfma_f32_16x16x32_bf16(      \
                af3, bfr[j][1], acc[(P)*2 + 1][j], 0, 0, 0);                  \
        }                                                                     \
        __builtin_amdgcn_s_setprio(0);                                        \
        if constexpr ((P) == 3 && (TAU) < 6)                                  \
            asm volatile("s_waitcnt vmcnt(4)" ::: "memory");                  \
        if constexpr ((P) == 3 && (TAU) == 6)                                 \
            asm volatile("s_waitcnt vmcnt(0)" ::: "memory");                  \
        __builtin_amdgcn_s_barrier();                                         \
        __builtin_amdgcn_sched_barrier(0);                                    \
    }
#define G1_TILE(TAU) \
    G1_PHASE(TAU, 0) G1_PHASE(TAU, 1) G1_PHASE(TAU, 2) G1_PHASE(TAU, 3)

    G1_TILE(0) G1_TILE(1) G1_TILE(2) G1_TILE(3)
    G1_TILE(4) G1_TILE(5) G1_TILE(6) G1_TILE(7)

#undef G1_PHASE
#undef G1_TILE

    // epilogue: j-outer / i-inner so each 64B h1 line is completed by 4
    // back-to-back 16B bursts (kills partial-line write amplification)
    float4 bb[8];
#pragma unroll
    for (int i = 0; i < 8; ++i)
        bb[i] = *(const float4*)&bias[m0 + wm + i * 16 + fq * 4];
#pragma unroll
    for (int j = 0; j < 4; ++j) {
        int xrow = n0 + wn + j * 16 + fr;
        uint8_t* dst = &h1[(size_t)xrow * ldh + m0 + wm + fq * 4];
#pragma unroll
        for (int i = 0; i < 8; ++i) {
            float t0 = fast_tanh(acc[i][j][0] + bb[i].x);
            float t1 = fast_tanh(acc[i][j][1] + bb[i].y);
            float t2 = fast_tanh(acc[i][j][2] + bb[i].z);
            float t3 = fast_tanh(acc[i][j][3] + bb[i].w);
            int p = 0;
            p = __builtin_amdgcn_cvt_pk_fp8_f32(t0, t1, p, false);
            p = __builtin_amdgcn_cvt_pk_fp8_f32(t2, t3, p, true);
            *(uint32_t*)(dst + i * 16) = (uint32_t)p;
        }
    }
}

// ------- layer 2+3 (fp8 x fp8, proven R4 version): eo += tanh(h1@W2+b)@We3 -------
// A = W2f8t rows (h2 cols, x32-scaled), B = h1 rows (fp8, col band e*1024).
__global__ __launch_bounds__(256, 4) void gemm2_kernel(
    const uint8_t* __restrict__ h1,    // [32768][6144] fp8
    const uint8_t* __restrict__ W2f8t, // [6][512][1024] fp8 (x32)
    const float* __restrict__ be2,     // [6][512]
    const float* __restrict__ We3,     // [6][512][3]
    float* __restrict__ eo,            // [6][32768][3]
    int ldh) {
    __shared__ __align__(16) uint8_t sA[128 * 64];
    __shared__ __align__(16) uint8_t sB[128 * 64];
    __shared__ float w3s[128 * 3];
    __shared__ float b2s[128];
    const int tid = threadIdx.x;
    const int w = tid >> 6, l = tid & 63;
    const int e  = blockIdx.z;
    const int n0 = blockIdx.x * 128;   // xrows
    const int m0 = blockIdx.y * 128;   // h2 cols (0..511)
    const int wm = (w & 1) * 64, wn = (w >> 1) * 64;
    const int srow4 = l >> 2;                         // dest row within 16-row group
    const int g4 = (((l & 3) ^ ((l >> 3) & 3)) << 4); // source granule (matches swz8)
    const int fr = l & 15, fq = l >> 4;
    const uint8_t* Ae = W2f8t + (size_t)e * (H2N * H1N);
    const uint8_t* Be = h1 + (size_t)e * H1N;   // column band within ldh=6144

    if (tid < 128) {
        int c = m0 + tid;
        b2s[tid] = be2[e * H2N + c];
        w3s[tid * 3 + 0] = We3[((size_t)e * H2N + c) * 3 + 0];
        w3s[tid * 3 + 1] = We3[((size_t)e * H2N + c) * 3 + 1];
        w3s[tid * 3 + 2] = We3[((size_t)e * H2N + c) * 3 + 2];
    }

    f32x4 acc[4][4];
#pragma unroll
    for (int i = 0; i < 4; ++i)
#pragma unroll
        for (int j = 0; j < 4; ++j) acc[i][j] = (f32x4){0.f, 0.f, 0.f, 0.f};

    for (int k0 = 0; k0 < H1N; k0 += 64) {
        __syncthreads();
#pragma unroll
        for (int jj = 0; jj < 2; ++jj) {
            int row = w * 32 + jj * 16 + srow4;
            gld16(Ae + (size_t)(m0 + row) * H1N + k0 + g4, sA + (w * 32 + jj * 16) * 64);
            gld16(Be + (size_t)(n0 + row) * ldh + k0 + g4, sB + (w * 32 + jj * 16) * 64);
        }
        __syncthreads();
#pragma unroll
        for (int ks = 0; ks < 2; ++ks) {
            i64v af[4], bfr[4];
#pragma unroll
            for (int i = 0; i < 4; ++i) {
                int row = wm + i * 16 + fr;
                af[i] = *(const i64v*)&sA[swz8(row, ks * 2 + (fq >> 1)) + ((fq & 1) << 3)];
            }
#pragma unroll
            for (int j = 0; j < 4; ++j) {
                int row = wn + j * 16 + fr;
                bfr[j] = *(const i64v*)&sB[swz8(row, ks * 2 + (fq >> 1)) + ((fq & 1) << 3)];
            }
#pragma unroll
            for (int i = 0; i < 4; ++i)
#pragma unroll
                for (int j = 0; j < 4; ++j)
                    acc[i][j] = __builtin_amdgcn_mfma_f32_16x16x32_fp8_fp8(
                        af[i], bfr[j], acc[i][j], 0, 0, 0);
        }
    }

    // lane holds 16 h2-cols of xrow; layer-3 col-sum in-register; acc is x32-scaled
    float p[4][3];
#pragma unroll
    for (int j = 0; j < 4; ++j) { p[j][0] = 0.f; p[j][1] = 0.f; p[j][2] = 0.f; }
#pragma unroll
    for (int i = 0; i < 4; ++i) {
        int cl = wm + i * 16 + fq * 4;   // local col 0..127
        float4 bb = *(const float4*)&b2s[cl];
        float4 wa = *(const float4*)&w3s[cl * 3 + 0];
        float4 wb = *(const float4*)&w3s[cl * 3 + 4];
        float4 wc = *(const float4*)&w3s[cl * 3 + 8];
        float bias4[4] = {bb.x, bb.y, bb.z, bb.w};
        float w30[4] = {wa.x, wa.w, wb.z, wc.y};
        float w31[4] = {wa.y, wb.x, wb.w, wc.z};
        float w32[4] = {wa.z, wb.y, wc.x, wc.w};
#pragma unroll
        for (int j = 0; j < 4; ++j) {
#pragma unroll
            for (int r = 0; r < 4; ++r) {
                float t = fast_tanh(acc[i][j][r] * W2INV + bias4[r]);
                p[j][0] += t * w30[r];
                p[j][1] += t * w31[r];
                p[j][2] += t * w32[r];
            }
        }
    }
#pragma unroll
    for (int j = 0; j < 4; ++j) {
        float v0 = p[j][0], v1 = p[j][1], v2 = p[j][2];
        v0 += __shfl_xor(v0, 16); v0 += __shfl_xor(v0, 32);
        v1 += __shfl_xor(v1, 16); v1 += __shfl_xor(v1, 32);
        v2 += __shfl_xor(v2, 16); v2 += __shfl_xor(v2, 32);
        if (fq == 0) {
            int xrow = n0 + wn + j * 16 + fr;
            float* dst = eo + ((size_t)e * NROWS + xrow) * 3;
            atomicAdd(dst + 0, v0);
            atomicAdd(dst + 1, v1);
            atomicAdd(dst + 2, v2);
        }
    }
}

// ---------------- final: routing-weighted mean + aggregator MLP ----------------
__global__ void final_kernel(
    const float* __restrict__ routing, const float* __restrict__ eo,
    const float* __restrict__ be3, const float* __restrict__ Wa1,
    const float* __restrict__ ba1, const float* __restrict__ Wa2,
    const float* __restrict__ ba2, float* __restrict__ out) {
    int b = blockIdx.x * blockDim.x + threadIdx.x;
    if (b >= NBATCH) return;
    float f0 = 0.f, f1 = 0.f, f2 = 0.f;
    for (int s = 0; s < 8; ++s) {
        int r = b * 8 + s;
        const float* rt = routing + (size_t)r * 6;
#pragma unroll
        for (int e = 0; e < 6; ++e) {
            float wgt = rt[e];
            const float* eop = eo + ((size_t)e * NROWS + r) * 3;
            f0 += wgt * (eop[0] + be3[e * 3 + 0]);
            f1 += wgt * (eop[1] + be3[e * 3 + 1]);
            f2 += wgt * (eop[2] + be3[e * 3 + 2]);
        }
    }
    f0 *= 0.125f; f1 *= 0.125f; f2 *= 0.125f;
    float o0 = ba2[0], o1 = ba2[1], o2 = ba2[2];
#pragma unroll
    for (int h = 0; h < 16; ++h) {
        float a = f0 * Wa1[h] + f1 * Wa1[16 + h] + f2 * Wa1[32 + h] + ba1[h];
        a = fmaxf(a, 0.f);
        o0 += a * Wa2[h * 3 + 0];
        o1 += a * Wa2[h * 3 + 1];
        o2 += a * Wa2[h * 3 + 2];
    }
    out[b * 3 + 0] = o0;
    out[b * 3 + 1] = o1;
    out[b * 3 + 2] = o2;
}

// ---------------- host ----------------

extern "C" void kernel_launch(void* const* d_in, const int* in_sizes, int n_in,
                              void* d_out, int out_size, void* d_ws, size_t ws_size,
                              hipStream_t stream) {
    const float* x   = (const float*)d_in[0];
    const float* Wr1 = (const float*)d_in[1];
    const float* br1 = (const float*)d_in[2];
    const float* Wr2 = (const float*)d_in[3];
    const float* br2 = (const float*)d_in[4];
    const float* We1 = (const float*)d_in[5];
    const float* be1 = (const float*)d_in[6];
    const float* We2 = (const float*)d_in[7];
    const float* be2 = (const float*)d_in[8];
    const float* We3 = (const float*)d_in[9];
    const float* be3 = (const float*)d_in[10];
    const float* Wa1 = (const float*)d_in[11];
    const float* ba1 = (const float*)d_in[12];
    const float* Wa2 = (const float*)d_in[13];
    const float* ba2 = (const float*)d_in[14];
    float* out = (float*)d_out;

    char* ws = (char*)d_ws;
    const size_t off_xbf  = 0;                               // 32768*512*2  = 33554432
    const size_t off_w1t  = off_xbf  + (size_t)33554432;     // 6*1024*512*2 = 6291456
    const size_t off_w2t  = off_w1t  + (size_t)6291456;      // 6*512*1024 fp8 (region 6291456)
    const size_t off_wr1t = off_w2t  + (size_t)6291456;      // 8*32*512*2   = 262144
    const size_t off_rout = off_wr1t + (size_t)262144;       // 32768*6*4    = 786432
    const size_t off_eo   = off_rout + (size_t)786432;       // 6*32768*3*4  = 2359296
    const size_t off_h1   = off_eo   + (size_t)2359296;      // base = 49545216

    // h1 fp8 [32768][6144] = 201.3 MB; total 250.9 MB
    if (off_h1 + (size_t)NROWS * HALL > ws_size) return;  // diagnostic

    bf16*    xbf     = (bf16*)(ws + off_xbf);
    bf16*    W1t     = (bf16*)(ws + off_w1t);
    uint8_t* W2f8t   = (uint8_t*)(ws + off_w2t);
    bf16*    Wr1t    = (bf16*)(ws + off_wr1t);
    float*   routing = (float*)(ws + off_rout);
    float*   eo      = (float*)(ws + off_eo);
    uint8_t* h1      = (uint8_t*)(ws + off_h1);

    // prep
    cvt_bf16_kernel<<<16384, 256, 0, stream>>>(x, xbf, 4194304);
    transpose_cvt<<<dim3(16, 8, 6), 256, 0, stream>>>(We1, W1t, 512, 1024);
    transpose_cvt_fp8<<<dim3(8, 16, 6), 256, 0, stream>>>(We2, W2f8t, 1024, 512, W2SCALE);
    transpose_cvt<<<dim3(1, 8, 8), 256, 0, stream>>>(Wr1, Wr1t, 512, 32);
    zero_f32_kernel<<<2304, 256, 0, stream>>>(eo, 589824);

    // router
    router_kernel<<<dim3(32, 8), 256, 0, stream>>>(xbf, Wr1t, br1, Wr2, br2, routing);

    // experts: gemm1 8-phase pipeline (512 thr), gemm2 proven R4 version
    gemm1_kernel<<<dim3(NROWS / 256, HALL / 256), 512, 0, stream>>>(
        W1t, xbf, be1, h1, HALL);
    gemm2_kernel<<<dim3(NROWS / 128, H2N / 128, NEXP), 256, 0, stream>>>(
        h1, W2f8t, be2, We3, eo, HALL);

    // aggregate
    final_kernel<<<16, 256, 0, stream>>>(routing, eo, be3, Wa1, ba1, Wa2, ba2, out);
}